// Round 2
// baseline (442.550 us; speedup 1.0000x reference)
//
#include <hip/hip_runtime.h>
#include <math.h>

// rFFT-512 via radix-2 Stockham on packed complex-256, one wave (64 lanes) per row.
// re[b,t,r] = sum_n x[n] cos(2*pi*r*n/512); im[b,t,r] = -sum_n x[n] sin(2*pi*r*n/512)
// == Re/Im of X[k] = sum_n x[n] e^{-2*pi*i*k*n/512}, k = 0..256.

#define NFFT 512
#define NH 256         // packed complex FFT size
#define NRFFT 257
#define RPB 4          // rows per block (one wave each)

__global__ __launch_bounds__(256) void rfft512_kernel(const float* __restrict__ x,
                                                      float* __restrict__ out_re,
                                                      float* __restrict__ out_im,
                                                      int nrows) {
    __shared__ float2 bufA[RPB][NH];
    __shared__ float2 bufB[RPB][NH];

    const int lane = threadIdx.x & 63;
    const int wid  = threadIdx.x >> 6;
    const int row  = blockIdx.x * RPB + wid;
    const bool live = (row < nrows);   // wave-uniform

    // ---- load row: x[2n],x[2n+1] pairs are exactly the row reinterpreted as float2
    if (live) {
        const float4* x4 = reinterpret_cast<const float4*>(x + (size_t)row * NFFT);
        float4* a4 = reinterpret_cast<float4*>(&bufA[wid][0]);
        a4[lane]      = x4[lane];
        a4[lane + 64] = x4[lane + 64];
    }
    __syncthreads();

    // ---- Stockham radix-2 forward FFT, n=256, 8 stages, ping-pong A<->B
    const float TWO_PI_OVER_256 = 0.0245436926061702596f;  // 2*pi/256
    float2* X = &bufA[wid][0];
    float2* Y = &bufB[wid][0];
    #pragma unroll
    for (int m = 1; m <= 128; m <<= 1) {
        if (live) {
            #pragma unroll
            for (int bb = 0; bb < 2; ++bb) {
                const int b = lane + bb * 64;       // butterfly index 0..127
                const int t = b & ~(m - 1);         // j*m  (twiddle numerator)
                const float2 c0 = X[b];
                const float2 c1 = X[b + 128];
                float s, c;
                sincosf(-(float)t * TWO_PI_OVER_256, &s, &c);  // e^{-2*pi*i*t/256}
                float2 sum = {c0.x + c1.x, c0.y + c1.y};
                float2 dif = {c0.x - c1.x, c0.y - c1.y};
                float2 tw  = {c * dif.x - s * dif.y, c * dif.y + s * dif.x};
                Y[b + t]     = sum;
                Y[b + t + m] = tw;
            }
        }
        float2* tmp = X; X = Y; Y = tmp;   // 8 swaps -> result ends in bufA
        __syncthreads();
    }

    // ---- untangle packed real FFT and store k = 0..256
    if (live) {
        const float TWO_PI_OVER_512 = 0.0122718463030851298f;  // 2*pi/512
        float* orr = out_re + (size_t)row * NRFFT;
        float* oir = out_im + (size_t)row * NRFFT;
        #pragma unroll
        for (int kk = 0; kk < 4; ++kk) {
            const int k = lane + kk * 64;
            if (k == 0) {
                const float2 z0 = X[0];
                orr[0]   = z0.x + z0.y;  oir[0]   = 0.0f;
                orr[256] = z0.x - z0.y;  oir[256] = 0.0f;
            } else {
                const float2 zk = X[k];
                const float2 zm = X[256 - k];
                const float ze_re = 0.5f * (zk.x + zm.x);
                const float ze_im = 0.5f * (zk.y - zm.y);
                const float zo_re = 0.5f * (zk.y + zm.y);
                const float zo_im = -0.5f * (zk.x - zm.x);
                float s, c;
                sincosf(-(float)k * TWO_PI_OVER_512, &s, &c);  // e^{-2*pi*i*k/512}
                orr[k] = ze_re + c * zo_re - s * zo_im;
                oir[k] = ze_im + c * zo_im + s * zo_re;
            }
        }
    }
}

extern "C" void kernel_launch(void* const* d_in, const int* in_sizes, int n_in,
                              void* d_out, int out_size, void* d_ws, size_t ws_size,
                              hipStream_t stream) {
    const float* x = (const float*)d_in[0];
    // d_in[1]/d_in[2] (m_real/m_imag) unused: twiddles computed analytically.
    float* out = (float*)d_out;
    const int nrows = in_sizes[0] / NFFT;            // 32*4000 = 128000
    float* out_re = out;
    float* out_im = out + (size_t)nrows * NRFFT;     // outputs concatenated flat
    const int blocks = (nrows + RPB - 1) / RPB;      // 32000
    rfft512_kernel<<<blocks, 256, 0, stream>>>(x, out_re, out_im, nrows);
}